// Round 2
// baseline (2344.263 us; speedup 1.0000x reference)
//
#include <hip/hip_runtime.h>
#include <math.h>

#define T_SEQ 2048
#define CDIM 1024
#define NH 16
#define NKV 4
#define HS 64

// ---------------- float atomics via CAS ----------------
__device__ __forceinline__ void atomicMinF(float* addr, float val) {
    unsigned int* ua = (unsigned int*)addr;
    unsigned int old = __float_as_uint(*addr);
    while (val < __uint_as_float(old)) {
        unsigned int assumed = old;
        old = atomicCAS(ua, assumed, __float_as_uint(val));
        if (old == assumed) break;
    }
}
__device__ __forceinline__ void atomicMaxF(float* addr, float val) {
    unsigned int* ua = (unsigned int*)addr;
    unsigned int old = __float_as_uint(*addr);
    while (val > __uint_as_float(old)) {
        unsigned int assumed = old;
        old = atomicCAS(ua, assumed, __float_as_uint(val));
        if (old == assumed) break;
    }
}

// ---------------- init: rope tables, FIRE tables, minmax slots ----------------
__global__ __launch_bounds__(256) void init_kernel(float* cosT, float* sinT, float* rdT,
                                                   float* pnT, float* mm,
                                                   const float* fire_c, const float* fire_L) {
    int i = blockIdx.x * 256 + threadIdx.x;
    float c = fire_c[0];
    float L = fabsf(fire_L[0]);
    if (i < T_SEQ * 32) {
        int t = i >> 5, j = i & 31;
        float inv = powf(10000.0f, -(float)j / 32.0f);
        float f = (float)t * inv;
        cosT[i] = cosf(f);
        sinT[i] = sinf(f);
    }
    if (i < T_SEQ) {
        rdT[i] = logf(fabsf(c * (float)i) + 1.0f);
        pnT[i] = logf(fabsf(c * fmaxf((float)i, L)) + 1.0f) + 1e-6f;
    }
    if (i < 16) mm[i] = (i & 1) ? -__builtin_inff() : __builtin_inff();
}

// ---------------- tiled fp32 GEMM: C(MxN) = A(MxK) @ B(KxN), all row-major ----------------
// 64x64 tile per 256-thread block, 4x4 microtile, BK=16. M%64==0, N%64==0, K%16==0.
#define BM 64
#define BN 64
#define BK 16
__global__ __launch_bounds__(256) void gemm_f32(const float* __restrict__ A,
                                                const float* __restrict__ B,
                                                float* __restrict__ C,
                                                int M, int N, int K) {
    __shared__ float As[BK][BM + 1];
    __shared__ float Bs[BK][BN + 1];
    int tid = threadIdx.x;
    int tx = tid & 15, ty = tid >> 4;
    int row0 = blockIdx.y * BM, col0 = blockIdx.x * BN;
    float acc[4][4] = {};
    for (int k0 = 0; k0 < K; k0 += BK) {
        for (int i = tid; i < BM * BK; i += 256) {
            int r = i / BK, cc = i % BK;
            As[cc][r] = A[(size_t)(row0 + r) * K + (k0 + cc)];
        }
        for (int i = tid; i < BN * BK; i += 256) {
            int r = i / BN, cc = i % BN;
            Bs[r][cc] = B[(size_t)(k0 + r) * N + (col0 + cc)];
        }
        __syncthreads();
        #pragma unroll
        for (int kk = 0; kk < BK; ++kk) {
            float a[4], b[4];
            #pragma unroll
            for (int i = 0; i < 4; ++i) a[i] = As[kk][ty * 4 + i];
            #pragma unroll
            for (int j = 0; j < 4; ++j) b[j] = Bs[kk][tx * 4 + j];
            #pragma unroll
            for (int i = 0; i < 4; ++i)
                #pragma unroll
                for (int j = 0; j < 4; ++j) acc[i][j] = fmaf(a[i], b[j], acc[i][j]);
        }
        __syncthreads();
    }
    #pragma unroll
    for (int i = 0; i < 4; ++i)
        #pragma unroll
        for (int j = 0; j < 4; ++j)
            C[(size_t)(row0 + ty * 4 + i) * N + (col0 + tx * 4 + j)] = acc[i][j];
}

// ---------------- RoPE in place + global min/max ----------------
// x: (T_SEQ, nh, 64). One thread handles the (d, d+32) pair.
__global__ __launch_bounds__(256) void rope_minmax_kernel(float* __restrict__ x,
                                                          const float* __restrict__ cosT,
                                                          const float* __restrict__ sinT,
                                                          int nh, float* mm) {
    int n = T_SEQ * nh * 32;
    float lmn = __builtin_inff(), lmx = -__builtin_inff();
    for (int i = blockIdx.x * 256 + threadIdx.x; i < n; i += gridDim.x * 256) {
        int d = i & 31;
        int th = i >> 5;
        int h = th % nh;
        int t = th / nh;
        float c = cosT[(t << 5) + d], s = sinT[(t << 5) + d];
        float* p = x + ((size_t)t * nh + h) * 64;
        float x1 = p[d], x2 = p[d + 32];
        float o1 = fmaf(x1, c, -x2 * s);
        float o2 = fmaf(x2, c, x1 * s);
        p[d] = o1;
        p[d + 32] = o2;
        lmn = fminf(lmn, fminf(o1, o2));
        lmx = fmaxf(lmx, fmaxf(o1, o2));
    }
    __shared__ float smn[256], smx[256];
    int tid = threadIdx.x;
    smn[tid] = lmn; smx[tid] = lmx;
    __syncthreads();
    for (int s2 = 128; s2; s2 >>= 1) {
        if (tid < s2) {
            smn[tid] = fminf(smn[tid], smn[tid + s2]);
            smx[tid] = fmaxf(smx[tid], smx[tid + s2]);
        }
        __syncthreads();
    }
    if (tid == 0) { atomicMinF(mm, smn[0]); atomicMaxF(mm + 1, smx[0]); }
}

// ---------------- plain global min/max ----------------
__global__ __launch_bounds__(256) void minmax_kernel(const float* __restrict__ x, int n, float* mm) {
    float lmn = __builtin_inff(), lmx = -__builtin_inff();
    for (int i = blockIdx.x * 256 + threadIdx.x; i < n; i += gridDim.x * 256) {
        float v = x[i];
        lmn = fminf(lmn, v);
        lmx = fmaxf(lmx, v);
    }
    __shared__ float smn[256], smx[256];
    int tid = threadIdx.x;
    smn[tid] = lmn; smx[tid] = lmx;
    __syncthreads();
    for (int s2 = 128; s2; s2 >>= 1) {
        if (tid < s2) {
            smn[tid] = fminf(smn[tid], smn[tid + s2]);
            smx[tid] = fmaxf(smx[tid], smx[tid + s2]);
        }
        __syncthreads();
    }
    if (tid == 0) { atomicMinF(mm, smn[0]); atomicMaxF(mm + 1, smx[0]); }
}

// ---------------- per-tensor affine fake-quant, in place ----------------
__global__ __launch_bounds__(256) void quant_kernel(float* __restrict__ x, int n,
                                                    const float* __restrict__ mm) {
    float mn = mm[0], mx = mm[1];
    float scale = (mx - mn) / 255.0f + 1e-12f;
    float zp = rintf(-mn / scale);
    for (int i = blockIdx.x * 256 + threadIdx.x; i < n; i += gridDim.x * 256) {
        float v = x[i];
        float qv = rintf(v / scale) + zp;
        qv = fminf(fmaxf(qv, 0.0f), 255.0f);
        x[i] = (qv - zp) * scale;
    }
}

// ---------------- attention: per (head, 4 q-rows) block ----------------
// q: (T,16,64) quantized+rope'd; k: (T,4,64); v: (T,4,64). y: (T,16,64).
// Phase 1: stage K tiles in LDS, compute scores+FIRE bias into LDS score row, track max.
// Softmax stats per row; att-quant is deterministic (scale=1/255, zp=0).
// Phase 2: stage V tiles, y[d] += round(p*255)/255 * V[k][d].
__global__ __launch_bounds__(256) void attn_kernel(
    const float* __restrict__ q, const float* __restrict__ k, const float* __restrict__ v,
    float* __restrict__ y, const float* __restrict__ rdT, const float* __restrict__ pnT,
    const float* __restrict__ w1, const float* __restrict__ b1,
    const float* __restrict__ w2, const float* __restrict__ b2) {
    __shared__ float S[4][T_SEQ];     // 32 KB score rows (then exp values)
    __shared__ float KV[64][65];      // 16.6 KB staged K/V tile (pad 65 -> conflict-free)
    __shared__ float Qs[4][64];
    __shared__ float W1s[32], B1s[32], W2s[512];

    int h = blockIdx.y;
    int g = h >> 2;                   // GQA: head h uses kv group h/4
    int r0 = blockIdx.x << 2;
    int tid = threadIdx.x;
    int w = tid >> 6;                 // wave id = local row
    int lane = tid & 63;
    int r = r0 + w;

    if (tid < 32) { W1s[tid] = w1[tid]; B1s[tid] = b1[tid]; }
    for (int i = tid; i < 512; i += 256) W2s[i] = w2[i];
    {
        int rr = tid >> 6, d = tid & 63;
        Qs[rr][d] = q[((size_t)(r0 + rr) * NH + h) * HS + d];
    }
    float b2h = b2[h];
    float inv_pn = 1.0f / pnT[r];
    int nt = (r0 >> 6) + 1;           // causal: tiles 0..r0/64
    float m_lane = -__builtin_inff();
    __syncthreads();

    // ---- phase 1: scores ----
    for (int tt = 0; tt < nt; ++tt) {
        for (int i = tid; i < 64 * 64; i += 256) {
            int kk = i >> 6, d = i & 63;
            KV[kk][d] = k[((size_t)(tt * 64 + kk) * NKV + g) * HS + d];
        }
        __syncthreads();
        int kidx = (tt << 6) + lane;
        float s;
        if (kidx <= r) {
            float acc = 0.0f;
            #pragma unroll
            for (int d = 0; d < 64; ++d) acc = fmaf(Qs[w][d], KV[lane][d], acc);
            // FIRE bias: nd = rd(r-k)/pn(r); 32-wide relu MLP
            float nd = rdT[r - kidx] * inv_pn;
            float bias = b2h;
            #pragma unroll
            for (int j = 0; j < 32; ++j) {
                float hj = fmaxf(fmaf(nd, W1s[j], B1s[j]), 0.0f);
                bias = fmaf(hj, W2s[(j << 4) + h], bias);
            }
            s = fmaf(acc, 0.125f, bias);
            m_lane = fmaxf(m_lane, s);
        } else {
            s = -__builtin_inff();
        }
        S[w][(tt << 6) + lane] = s;
        __syncthreads();
    }

    // ---- softmax stats (per wave = per row) ----
    float m = m_lane;
    #pragma unroll
    for (int off = 32; off >= 1; off >>= 1) m = fmaxf(m, __shfl_xor(m, off));
    float lsum = 0.0f;
    int kn = nt << 6;
    for (int i = lane; i < kn; i += 64) {
        float s = S[w][i];
        float e = (s > -__builtin_inff()) ? expf(s - m) : 0.0f;
        S[w][i] = e;
        lsum += e;
    }
    #pragma unroll
    for (int off = 32; off >= 1; off >>= 1) lsum += __shfl_xor(lsum, off);
    float inv_l = 1.0f / lsum;
    __syncthreads();

    // ---- phase 2: quantized att @ V ----
    float yacc = 0.0f;                 // lane = output dim d
    for (int tt = 0; tt < nt; ++tt) {
        for (int i = tid; i < 64 * 64; i += 256) {
            int kk = i >> 6, d = i & 63;
            KV[kk][d] = v[((size_t)(tt * 64 + kk) * NKV + g) * HS + d];
        }
        __syncthreads();
        int kmax = min(64, r - (tt << 6) + 1);
        for (int kk = 0; kk < kmax; ++kk) {
            float p = S[w][(tt << 6) + kk] * inv_l;
            // fake_quant(att): min=0 max=1 exactly -> scale=1/255, zp=0
            float ph = fminf(rintf(p * 255.0f), 255.0f) * (1.0f / 255.0f);
            yacc = fmaf(ph, KV[kk][lane], yacc);
        }
        __syncthreads();
    }
    y[((size_t)r * NH + h) * HS + lane] = yacc;
}

extern "C" void kernel_launch(void* const* d_in, const int* in_sizes, int n_in,
                              void* d_out, int out_size, void* d_ws, size_t ws_size,
                              hipStream_t stream) {
    const float* x     = (const float*)d_in[0];
    const float* Wq    = (const float*)d_in[1];
    const float* Wk    = (const float*)d_in[2];
    const float* Wv    = (const float*)d_in[3];
    const float* Wproj = (const float*)d_in[4];
    const float* fw1   = (const float*)d_in[5];
    const float* fb1   = (const float*)d_in[6];
    const float* fw2   = (const float*)d_in[7];
    const float* fb2   = (const float*)d_in[8];
    const float* fc    = (const float*)d_in[9];
    const float* fL    = (const float*)d_in[10];
    float* out = (float*)d_out;

    float* ws   = (float*)d_ws;
    float* q    = ws;                  // 2097152  (T,16,64)
    float* kk   = q + 2097152;         // 524288   (T,4,64)
    float* vv   = kk + 524288;         // 524288
    float* y    = vv + 524288;         // 2097152
    float* cosT = y + 2097152;         // 65536
    float* sinT = cosT + 65536;        // 65536
    float* rdT  = sinT + 65536;        // 2048
    float* pnT  = rdT + 2048;          // 2048
    float* mm   = pnT + 2048;          // 16  [qmn,qmx,kmn,kmx,vmn,vmx,ymn,ymx]

    init_kernel<<<256, 256, 0, stream>>>(cosT, sinT, rdT, pnT, mm, fc, fL);

    dim3 gq(CDIM / 64, T_SEQ / 64);    // (16,32)
    dim3 gk(256 / 64, T_SEQ / 64);     // (4,32)
    gemm_f32<<<gq, 256, 0, stream>>>(x, Wq, q, T_SEQ, CDIM, CDIM);
    gemm_f32<<<gk, 256, 0, stream>>>(x, Wk, kk, T_SEQ, 256, CDIM);
    gemm_f32<<<gk, 256, 0, stream>>>(x, Wv, vv, T_SEQ, 256, CDIM);

    rope_minmax_kernel<<<1024, 256, 0, stream>>>(q, cosT, sinT, NH, mm + 0);
    rope_minmax_kernel<<<512, 256, 0, stream>>>(kk, cosT, sinT, NKV, mm + 2);
    minmax_kernel<<<512, 256, 0, stream>>>(vv, 524288, mm + 4);

    quant_kernel<<<1024, 256, 0, stream>>>(q, 2097152, mm + 0);
    quant_kernel<<<512, 256, 0, stream>>>(kk, 524288, mm + 2);
    quant_kernel<<<512, 256, 0, stream>>>(vv, 524288, mm + 4);

    dim3 ga(T_SEQ / 4, NH);
    attn_kernel<<<ga, 256, 0, stream>>>(q, kk, vv, y, rdT, pnT, fw1, fb1, fw2, fb2);

    minmax_kernel<<<1024, 256, 0, stream>>>(y, 2097152, mm + 6);
    quant_kernel<<<1024, 256, 0, stream>>>(y, 2097152, mm + 6);

    gemm_f32<<<gq, 256, 0, stream>>>(y, Wproj, out, T_SEQ, CDIM, CDIM);
}

// Round 7
// 520.981 us; speedup vs baseline: 4.4997x; 4.4997x over previous
//
#include <hip/hip_runtime.h>
#include <math.h>

#define T_SEQ 2048
#define CDIM 1024
#define NH 16
#define NKV 4
#define HS 64
#define FIRE_N 1024   // interpolation intervals; table has FIRE_N+1 entries

typedef __attribute__((ext_vector_type(8))) short bf16x8;
typedef __attribute__((ext_vector_type(4))) float f32x4;
typedef __attribute__((ext_vector_type(4))) unsigned short ushort4v;

__device__ __forceinline__ unsigned short f2bf(float f) {
    unsigned int u = __float_as_uint(f);
    u += 0x7fff + ((u >> 16) & 1);   // RNE
    return (unsigned short)(u >> 16);
}

// ---------------- float atomics via CAS ----------------
__device__ __forceinline__ void atomicMinF(float* addr, float val) {
    unsigned int* ua = (unsigned int*)addr;
    unsigned int old = __float_as_uint(*addr);
    while (val < __uint_as_float(old)) {
        unsigned int assumed = old;
        old = atomicCAS(ua, assumed, __float_as_uint(val));
        if (old == assumed) break;
    }
}
__device__ __forceinline__ void atomicMaxF(float* addr, float val) {
    unsigned int* ua = (unsigned int*)addr;
    unsigned int old = __float_as_uint(*addr);
    while (val > __uint_as_float(old)) {
        unsigned int assumed = old;
        old = atomicCAS(ua, assumed, __float_as_uint(val));
        if (old == assumed) break;
    }
}

// ---------------- init: rope tables, FIRE 1-D tables, minmax slots ----------------
__global__ __launch_bounds__(256) void init_kernel(float* cosT, float* sinT, float* rdT,
                                                   float* pnT, float* mm,
                                                   const float* fire_c, const float* fire_L) {
    int i = blockIdx.x * 256 + threadIdx.x;
    float c = fire_c[0];
    float L = fabsf(fire_L[0]);
    if (i < T_SEQ * 32) {
        int t = i >> 5, j = i & 31;
        float inv = powf(10000.0f, -(float)j / 32.0f);
        float f = (float)t * inv;
        cosT[i] = cosf(f);
        sinT[i] = sinf(f);
    }
    if (i < T_SEQ) {
        rdT[i] = logf(fabsf(c * (float)i) + 1.0f);
        pnT[i] = logf(fabsf(c * fmaxf((float)i, L)) + 1.0f) + 1e-6f;
    }
    if (i < 16) mm[i] = (i & 1) ? -__builtin_inff() : __builtin_inff();
}

// ---------------- FIRE bias(nd) piecewise-linear table, per head ----------------
__global__ __launch_bounds__(256) void fire_table_kernel(float* __restrict__ fireT,
    const float* __restrict__ w1, const float* __restrict__ b1,
    const float* __restrict__ w2, const float* __restrict__ b2,
    const float* __restrict__ fc, const float* __restrict__ fL) {
    int h = blockIdx.x;
    float cc = fabsf(fc[0]), LL = fabsf(fL[0]);
    float pn_min = logf(cc * LL + 1.0f) + 1e-6f;
    float ndmax = logf(cc * 2047.0f + 1.0f) / pn_min;
    float step = (ndmax > 1e-30f) ? (ndmax / (float)FIRE_N) : 0.0f;
    float b2h = b2[h];
    for (int i = threadIdx.x; i < FIRE_N + 1; i += 256) {
        float nd = step * (float)i;
        float acc = b2h;
        #pragma unroll
        for (int j = 0; j < 32; ++j)
            acc += fmaxf(fmaf(nd, w1[j], b1[j]), 0.0f) * w2[j * NH + h];
        fireT[h * (FIRE_N + 1) + i] = acc;
    }
}

// ---------------- fp32 -> bf16 elementwise convert ----------------
__global__ __launch_bounds__(256) void cvt_bf16_kernel(const float* __restrict__ in,
                                                       unsigned short* __restrict__ out, int n4) {
    for (int i = blockIdx.x * 256 + threadIdx.x; i < n4; i += gridDim.x * 256) {
        float4 v = ((const float4*)in)[i];
        ushort4v o;
        o[0] = f2bf(v.x); o[1] = f2bf(v.y); o[2] = f2bf(v.z); o[3] = f2bf(v.w);
        ((ushort4v*)out)[i] = o;
    }
}

// ---------------- transpose + convert: in (R x C fp32) -> out (C x R bf16) ----------------
// grid: (C/64, R/64), 256 threads.
__global__ __launch_bounds__(256) void transpose_bf16_kernel(const float* __restrict__ in,
                                                             unsigned short* __restrict__ out,
                                                             int R, int C) {
    __shared__ float t[64][65];
    int c0 = blockIdx.x * 64, r0 = blockIdx.y * 64;
    int tid = threadIdx.x;
    int lr = tid >> 6, lc = tid & 63;
    #pragma unroll 4
    for (int i = 0; i < 16; ++i)
        t[lr + 4 * i][lc] = in[(size_t)(r0 + lr + 4 * i) * C + c0 + lc];
    __syncthreads();
    #pragma unroll 4
    for (int i = 0; i < 16; ++i)
        out[(size_t)(c0 + lr + 4 * i) * R + r0 + lc] = f2bf(t[lc][lr + 4 * i]);
}

// ---------------- bf16 MFMA GEMM: C(MxN fp32) = A(MxK bf16) @ Bt(NxK bf16)^T ----------------
// 128x128 tile, 4 waves each owning a 64x64 quadrant, BK=32 (one MFMA depth).
// LDS rows padded to 40 elems (80B) -> 2-way bank aliasing only (free).
__global__ __launch_bounds__(256) void gemm_bf16(const unsigned short* __restrict__ A,
                                                 const unsigned short* __restrict__ Bt,
                                                 float* __restrict__ C,
                                                 int M, int N, int K) {
    __shared__ unsigned short As[128 * 40];
    __shared__ unsigned short Bs[128 * 40];
    const int tid = threadIdx.x;
    const int row0 = blockIdx.y * 128, col0 = blockIdx.x * 128;
    const int wv = tid >> 6, lane = tid & 63;
    const int l15 = lane & 15, l4 = lane >> 4;
    const int wr = (wv >> 1) * 64, wc = (wv & 1) * 64;
    f32x4 acc[4][4];
    #pragma unroll
    for (int n = 0; n < 4; ++n)
        #pragma unroll
        for (int m = 0; m < 4; ++m) acc[n][m] = (f32x4){0.f, 0.f, 0.f, 0.f};

    for (int k0 = 0; k0 < K; k0 += 32) {
        #pragma unroll
        for (int t2 = 0; t2 < 2; ++t2) {
            int c = tid + t2 * 256;
            int r = c >> 2, qq = c & 3;
            uint4 av = *(const uint4*)(A + (size_t)(row0 + r) * K + k0 + qq * 8);
            *(uint4*)(As + r * 40 + qq * 8) = av;
            uint4 bv = *(const uint4*)(Bt + (size_t)(col0 + r) * K + k0 + qq * 8);
            *(uint4*)(Bs + r * 40 + qq * 8) = bv;
        }
        __syncthreads();
        bf16x8 af[4], bfr[4];
        #pragma unroll
        for (int n = 0; n < 4; ++n) af[n] = *(const bf16x8*)(As + (wr + n * 16 + l15) * 40 + l4 * 8);
        #pragma unroll
        for (int m = 0; m < 4; ++m) bfr[m] = *(const bf16x8*)(Bs + (wc + m * 16 + l15) * 40 + l4 * 8);
        #pragma unroll
        for (int n = 0; n < 4; ++n)
            #pragma unroll
            for (int m = 0; m < 4; ++m)
                acc[n][m] = __builtin_amdgcn_mfma_f32_16x16x32_bf16(af[n], bfr[m], acc[n][m], 0, 0, 0);
        __syncthreads();
    }
    // C/D layout (m89/m91-verified): col = lane&15 (B index), row = (lane>>4)*4 + reg (A index)
    #pragma unroll
    for (int n = 0; n < 4; ++n) {
        #pragma unroll
        for (int m = 0; m < 4; ++m) {
            #pragma unroll
            for (int j = 0; j < 4; ++j) {
                C[(size_t)(row0 + wr + n * 16 + l4 * 4 + j) * N + col0 + wc + m * 16 + l15] = acc[n][m][j];
            }
        }
    }
}

// ---------------- RoPE in place + global min/max ----------------
__global__ __launch_bounds__(256) void rope_minmax_kernel(float* __restrict__ x,
                                                          const float* __restrict__ cosT,
                                                          const float* __restrict__ sinT,
                                                          int nh, float* mm) {
    int n = T_SEQ * nh * 32;
    float lmn = __builtin_inff(), lmx = -__builtin_inff();
    for (int i = blockIdx.x * 256 + threadIdx.x; i < n; i += gridDim.x * 256) {
        int d = i & 31;
        int th = i >> 5;
        int h = th % nh;
        int t = th / nh;
        float c = cosT[(t << 5) + d], s = sinT[(t << 5) + d];
        float* p = x + ((size_t)t * nh + h) * 64;
        float x1 = p[d], x2 = p[d + 32];
        float o1 = fmaf(x1, c, -x2 * s);
        float o2 = fmaf(x2, c, x1 * s);
        p[d] = o1;
        p[d + 32] = o2;
        lmn = fminf(lmn, fminf(o1, o2));
        lmx = fmaxf(lmx, fmaxf(o1, o2));
    }
    __shared__ float smn[256], smx[256];
    int tid = threadIdx.x;
    smn[tid] = lmn; smx[tid] = lmx;
    __syncthreads();
    for (int s2 = 128; s2; s2 >>= 1) {
        if (tid < s2) {
            smn[tid] = fminf(smn[tid], smn[tid + s2]);
            smx[tid] = fmaxf(smx[tid], smx[tid + s2]);
        }
        __syncthreads();
    }
    if (tid == 0) { atomicMinF(mm, smn[0]); atomicMaxF(mm + 1, smx[0]); }
}

// ---------------- plain global min/max ----------------
__global__ __launch_bounds__(256) void minmax_kernel(const float* __restrict__ x, int n, float* mm) {
    float lmn = __builtin_inff(), lmx = -__builtin_inff();
    for (int i = blockIdx.x * 256 + threadIdx.x; i < n; i += gridDim.x * 256) {
        float v = x[i];
        lmn = fminf(lmn, v);
        lmx = fmaxf(lmx, v);
    }
    __shared__ float smn[256], smx[256];
    int tid = threadIdx.x;
    smn[tid] = lmn; smx[tid] = lmx;
    __syncthreads();
    for (int s2 = 128; s2; s2 >>= 1) {
        if (tid < s2) {
            smn[tid] = fminf(smn[tid], smn[tid + s2]);
            smx[tid] = fmaxf(smx[tid], smx[tid + s2]);
        }
        __syncthreads();
    }
    if (tid == 0) { atomicMinF(mm, smn[0]); atomicMaxF(mm + 1, smx[0]); }
}

// ---------------- fake-quant fp32 -> bf16 out (for q,k,v,y) ----------------
__global__ __launch_bounds__(256) void quant_bf16_kernel(const float* __restrict__ x, int n,
                                                         const float* __restrict__ mm,
                                                         unsigned short* __restrict__ out) {
    float mn = mm[0], mx = mm[1];
    float scale = (mx - mn) / 255.0f + 1e-12f;
    float zp = rintf(-mn / scale);
    for (int i = blockIdx.x * 256 + threadIdx.x; i < n; i += gridDim.x * 256) {
        float v = x[i];
        float qv = rintf(v / scale) + zp;
        qv = fminf(fmaxf(qv, 0.0f), 255.0f);
        out[i] = f2bf((qv - zp) * scale);
    }
}

// ---------------- MFMA flash attention ----------------
// Block: (q-tile of 64 rows, head). 4 waves; wave w owns q-rows [16w,16w+16).
// Pass A: online softmax stats (m,l) per row via 16x16x32 bf16 MFMA scores.
// Pass B: recompute scores, p=exp(s-m)/l quantized (scale=1/255,zp=0 exact),
//         P staged in LDS -> A-frags, V staged transposed -> B-frags, MFMA PV.
// All LDS tiles XOR-swizzled (byte ^= (row&7)<<4) -> conflict-free b128 reads.
__global__ __launch_bounds__(256) void attn_mfma(
    const unsigned short* __restrict__ qb, const unsigned short* __restrict__ kb,
    const unsigned short* __restrict__ vb, float* __restrict__ y,
    const float* __restrict__ rdT, const float* __restrict__ pnT,
    const float* __restrict__ fireT,
    const float* __restrict__ fc, const float* __restrict__ fL) {
    __shared__ __align__(16) char Ks[8192];
    __shared__ __align__(16) char Vt[8192];
    __shared__ __align__(16) char Ps[8192];
    __shared__ float biasT[FIRE_N + 1];
    __shared__ float rdS[T_SEQ];

    const int h = blockIdx.y, g = h >> 2;
    const int qt = blockIdx.x;
    const int q0 = qt << 6;
    const int tid = threadIdx.x;
    const int w = tid >> 6, lane = tid & 63;
    const int l15 = lane & 15, l4 = lane >> 4;

    for (int i = tid; i < FIRE_N + 1; i += 256) biasT[i] = fireT[h * (FIRE_N + 1) + i];
    for (int i = tid; i < T_SEQ; i += 256) rdS[i] = rdT[i];

    float cc = fabsf(fc[0]), LL = fabsf(fL[0]);
    float pn_min = logf(cc * LL + 1.0f) + 1e-6f;
    float ndmax = logf(cc * 2047.0f + 1.0f) / pn_min;
    float inv_step = (ndmax > 1e-30f) ? ((float)FIRE_N / ndmax) : 0.0f;

    int qrow[4]; float invpn[4], mreg[4], lreg[4];
    #pragma unroll
    for (int r = 0; r < 4; ++r) {
        qrow[r] = q0 + (w << 4) + (l4 << 2) + r;
        invpn[r] = 1.0f / pnT[qrow[r]];
        mreg[r] = -3.0e38f; lreg[r] = 0.0f;
    }

    // Q A-fragments kept in registers for the whole kernel
    bf16x8 qa[2];
    {
        int qr = q0 + (w << 4) + l15;
        const unsigned short* qp = qb + ((size_t)qr * NH + h) * HS + (l4 << 3);
        qa[0] = *(const bf16x8*)(qp);
        qa[1] = *(const bf16x8*)(qp + 32);
    }

    const int krow = tid >> 2, kqtr = tid & 3;        // K staging role
    const int ksw = (krow & 7) << 4;
    const int vk = tid & 63, vd0 = (tid >> 6) << 4;   // V staging role

    __syncthreads();

    // ---------------- pass A: online m,l ----------------
    for (int tt = 0; tt <= qt; ++tt) {
        {
            const unsigned short* kp = kb + (((size_t)((tt << 6) + krow) * NKV + g) << 6) + (kqtr << 4);
            uint4 a = *(const uint4*)(kp);
            uint4 b = *(const uint4*)(kp + 8);
            *(uint4*)(Ks + krow * 128 + ((kqtr << 5) ^ ksw)) = a;
            *(uint4*)(Ks + krow * 128 + (((kqtr << 5) + 16) ^ ksw)) = b;
        }
        __syncthreads();
        f32x4 s[4];
        #pragma unroll
        for (int n = 0; n < 4; ++n) s[n] = (f32x4){0.f, 0.f, 0.f, 0.f};
        #pragma unroll
        for (int ks = 0; ks < 2; ++ks) {
            int cb = (l4 << 4) + (ks << 6);
            #pragma unroll
            for (int n = 0; n < 4; ++n) {
                int rowk = (n << 4) + l15;
                bf16x8 kf = *(const bf16x8*)(Ks + rowk * 128 + (cb ^ ((rowk & 7) << 4)));
                s[n] = __builtin_amdgcn_mfma_f32_16x16x32_bf16(qa[ks], kf, s[n], 0, 0, 0);
            }
        }
        #pragma unroll
        for (int n = 0; n < 4; ++n) {
            int kidx = (tt << 6) + (n << 4) + l15;
            #pragma unroll
            for (int r = 0; r < 4; ++r) {
                float v;
                if (kidx <= qrow[r]) {
                    float nd = rdS[qrow[r] - kidx] * invpn[r];
                    float u = nd * inv_step;
                    int iu = (int)u; iu = min(iu, FIRE_N - 1);
                    float fr = u - (float)iu;
                    float b0 = biasT[iu];
                    v = fmaf(s[n][r], 0.125f, fmaf(fr, biasT[iu + 1] - b0, b0));
                } else v = -3.0e38f;
                s[n][r] = v;
            }
        }
        #pragma unroll
        for (int r = 0; r < 4; ++r) {
            float tmax = fmaxf(fmaxf(s[0][r], s[1][r]), fmaxf(s[2][r], s[3][r]));
            tmax = fmaxf(tmax, __shfl_xor(tmax, 1));
            tmax = fmaxf(tmax, __shfl_xor(tmax, 2));
            tmax = fmaxf(tmax, __shfl_xor(tmax, 4));
            tmax = fmaxf(tmax, __shfl_xor(tmax, 8));
            float mnew = fmaxf(mreg[r], tmax);
            float es = __expf(s[0][r] - mnew) + __expf(s[1][r] - mnew)
                     + __expf(s[2][r] - mnew) + __expf(s[3][r] - mnew);
            es += __shfl_xor(es, 1); es += __shfl_xor(es, 2);
            es += __shfl_xor(es, 4); es += __shfl_xor(es, 8);
            lreg[r] = lreg[r] * __expf(mreg[r] - mnew) + es;
            mreg[r] = mnew;
        }
        __syncthreads();
    }

    float invl[4];
    #pragma unroll
    for (int r = 0; r < 4; ++r) invl[r] = 1.0f / lreg[r];

    // ---------------- pass B: recompute scores, quantized PV ----------------
    f32x4 yacc[4];
    #pragma unroll
    for (int n = 0; n < 4; ++n) yacc[n] = (f32x4){0.f, 0.f, 0.f, 0.f};

    for (int tt = 0; tt <= qt; ++tt) {
        {   // stage K
            const unsigned short* kp = kb + (((size_t)((tt << 6) + krow) * NKV + g) << 6) + (kqtr << 4);
            uint4 a = *(const uint4*)(kp);
            uint4 b = *(const uint4*)(kp + 8);
            *(uint4*)(Ks + krow * 128 + ((kqtr << 5) ^ ksw)) = a;
            *(uint4*)(Ks + krow * 128 + (((kqtr << 5) + 16) ^ ksw)) = b;
        }
        {   // stage V transposed: Vt[d][k]
            const unsigned short* vp = vb + (((size_t)((tt << 6) + vk) * NKV + g) << 6) + vd0;
            uint4 a = *(const uint4*)(vp);
            uint4 b = *(const uint4*)(vp + 8);
            unsigned int wv[8] = {a.x, a.y, a.z, a.w, b.x, b.y, b.z, b.w};
            int k2 = vk << 1;
            #pragma unroll
            for (int i = 0; i < 8; ++i) {
                int d = vd0 + (i << 1);
                *(unsigned short*)(Vt + d * 128 + (k2 ^ ((d & 7) << 4))) = (unsigned short)(wv[i] & 0xffff);
                int d1 = d + 1;
                *(unsigned short*)(Vt + d1 * 128 + (k2 ^ ((d1 & 7) << 4))) = (unsigned short)(wv[i] >> 16);
            }
        }
        __syncthreads();
        f32x4 s[4];
        #pragma unroll
        for (int n = 0; n < 4; ++n) s[n] = (f32x4){0.f, 0.f, 0.f, 0.f};
        #pragma unroll
        for (int ks = 0; ks < 2; ++ks) {
            int cb = (l4 << 4) + (ks << 6);
            #pragma unroll
            for (int n = 0; n < 4; ++n) {
                int rowk = (n << 4) + l15;
                bf16x8 kf = *(const bf16x8*)(Ks + rowk * 128 + (cb ^ ((rowk & 7) << 4)));
                s[n] = __builtin_amdgcn_mfma_f32_16x16x32_bf16(qa[ks], kf, s[n], 0, 0, 0);
            }
        }
        #pragma unroll
        for (int n = 0; n < 4; ++n) {
            int kidx = (tt << 6) + (n << 4) + l15;
            #pragma unroll
            for (int r = 0; r < 4; ++r) {
                float v;
                if (kidx <= qrow[r]) {
                    float nd = rdS[qrow[r] - kidx] * invpn[r];
                    float u = nd * inv_step;
                    int iu = (int)u; iu = min(iu, FIRE_N - 1);
                    float fr = u - (float)iu;
                    float b0 = biasT[iu];
                    v = fmaf(s[n][r], 0.125f, fmaf(fr, biasT[iu + 1] - b0, b0));
                } else v = -3.0e38f;
                s[n][r] = v;
            }
        }
        // p = exp(s-m)/l, quantize to 1/255 grid, stage as bf16 A-operand
        #pragma unroll
        for (int n = 0; n < 4; ++n) {
            #pragma unroll
            for (int r = 0; r < 4; ++r) {
                float p = __expf(s[n][r] - mreg[r]) * invl[r];
                float ph = fminf(rintf(p * 255.0f), 255.0f) * (1.0f / 255.0f);
                int rowp = (w << 4) + (l4 << 2) + r;
                *(unsigned short*)(Ps + rowp * 128 + ((((n << 4) + l15) << 1) ^ ((rowp & 7) << 4))) = f2bf(ph);
            }
        }
        __syncthreads();
        #pragma unroll
        for (int ks = 0; ks < 2; ++ks) {
            int rowp = (w << 4) + l15;
            int cb = (l4 << 4) + (ks << 6);
            bf16x8 pa = *(const bf16x8*)(Ps + rowp * 128 + (cb ^ ((rowp & 7) << 4)));
            #pragma unroll
            for (int n2 = 0; n2 < 4; ++n2) {
                int d = (n2 << 4) + l15;
                bf16x8 vf = *(const bf16x8*)(Vt + d * 128 + (cb ^ ((d & 7) << 4)));
                yacc[n2] = __builtin_amdgcn_mfma_f32_16x16x32_bf16(pa, vf, yacc[n2], 0, 0, 0);
            }
        }
        __syncthreads();
    }

    #pragma unroll
    for (int n2 = 0; n2 < 4; ++n2)
        #pragma unroll
        for (int r = 0; r < 4; ++r)
            y[((size_t)qrow[r] * NH + h) * HS + (n2 << 4) + l15] = yacc[n2][r];
}

extern "C" void kernel_launch(void* const* d_in, const int* in_sizes, int n_in,
                              void* d_out, int out_size, void* d_ws, size_t ws_size,
                              hipStream_t stream) {
    const float* x     = (const float*)d_in[0];
    const float* Wq    = (const float*)d_in[1];
    const float* Wk    = (const float*)d_in[2];
    const float* Wv    = (const float*)d_in[3];
    const float* Wproj = (const float*)d_in[4];
    const float* fw1   = (const float*)d_in[5];
    const float* fb1   = (const float*)d_in[6];
    const float* fw2   = (const float*)d_in[7];
    const float* fb2   = (const float*)d_in[8];
    const float* fc    = (const float*)d_in[9];
    const float* fL    = (const float*)d_in[10];
    float* out = (float*)d_out;

    float* ws   = (float*)d_ws;
    float* qf   = ws;                  // (T,16,64) fp32 q; REUSED as y after quant
    float* kkf  = qf + 2097152;        // (T,4,64) fp32
    float* vvf  = kkf + 524288;
    float* cosT = vvf + 524288;
    float* sinT = cosT + 65536;
    float* rdT  = sinT + 65536;
    float* pnT  = rdT + 2048;
    float* mm   = pnT + 2048;          // [qmn,qmx,kmn,kmx,vmn,vmx,ymn,ymx]
    float* fireT = mm + 16;            // 16*(FIRE_N+1)
    unsigned short* qb  = (unsigned short*)(fireT + 16 * (FIRE_N + 1));
    unsigned short* kb  = qb + 2097152;
    unsigned short* vb  = kb + 524288;
    unsigned short* xb  = vb + 524288;       // (T,1024) bf16; REUSED as yb
    unsigned short* Wqt = xb + 2097152;      // (1024,1024) bf16 transposed
    unsigned short* Wkt = Wqt + 1048576;     // (256,1024)
    unsigned short* Wvt = Wkt + 262144;      // (256,1024)
    unsigned short* Wpt = Wvt + 262144;      // (1024,1024)
    float* y  = qf;                    // alias: q fp32 dead after quant_bf16
    unsigned short* yb = xb;           // alias: xb dead after projections

    init_kernel<<<256, 256, 0, stream>>>(cosT, sinT, rdT, pnT, mm, fc, fL);
    fire_table_kernel<<<16, 256, 0, stream>>>(fireT, fw1, fb1, fw2, fb2, fc, fL);

    // convert x and transpose+convert weights to bf16
    cvt_bf16_kernel<<<1024, 256, 0, stream>>>(x, xb, 524288);
    transpose_bf16_kernel<<<dim3(16, 16), 256, 0, stream>>>(Wq, Wqt, 1024, 1024);
    transpose_bf16_kernel<<<dim3(4, 16), 256, 0, stream>>>(Wk, Wkt, 1024, 256);
    transpose_bf16_kernel<<<dim3(4, 16), 256, 0, stream>>>(Wv, Wvt, 1024, 256);
    transpose_bf16_kernel<<<dim3(16, 16), 256, 0, stream>>>(Wproj, Wpt, 1024, 1024);

    // projections (MFMA)
    gemm_bf16<<<dim3(8, 16), 256, 0, stream>>>(xb, Wqt, qf, T_SEQ, CDIM, CDIM);
    gemm_bf16<<<dim3(2, 16), 256, 0, stream>>>(xb, Wkt, kkf, T_SEQ, 256, CDIM);
    gemm_bf16<<<dim3(2, 16), 256, 0, stream>>>(xb, Wvt, vvf, T_SEQ, 256, CDIM);

    rope_minmax_kernel<<<1024, 256, 0, stream>>>(qf, cosT, sinT, NH, mm + 0);
    rope_minmax_kernel<<<512, 256, 0, stream>>>(kkf, cosT, sinT, NKV, mm + 2);
    minmax_kernel<<<512, 256, 0, stream>>>(vvf, 524288, mm + 4);

    quant_bf16_kernel<<<1024, 256, 0, stream>>>(qf, 2097152, mm + 0, qb);
    quant_bf16_kernel<<<512, 256, 0, stream>>>(kkf, 524288, mm + 2, kb);
    quant_bf16_kernel<<<512, 256, 0, stream>>>(vvf, 524288, mm + 4, vb);

    dim3 ga(T_SEQ / 64, NH);
    attn_mfma<<<ga, 256, 0, stream>>>(qb, kb, vb, y, rdT, pnT, fireT, fc, fL);

    minmax_kernel<<<1024, 256, 0, stream>>>(y, 2097152, mm + 6);
    quant_bf16_kernel<<<1024, 256, 0, stream>>>(y, 2097152, mm + 6, yb);

    // output projection (MFMA)
    gemm_bf16<<<dim3(8, 16), 256, 0, stream>>>(yb, Wpt, out, T_SEQ, CDIM, CDIM);
}